// Round 16
// baseline (41.211 us; speedup 1.0000x reference)
//
#include <hip/hip_runtime.h>

typedef _Float16 f16x8 __attribute__((ext_vector_type(8)));
typedef float f32x4 __attribute__((ext_vector_type(4)));
typedef float fvec4 __attribute__((ext_vector_type(4)));  // clang-native for nt-load

// ---------------- gate primitives (state: 128 amps, 2 per lane) -------------
// amp index i = (r<<6) | lane, wire w <-> bit (6-w) (wire 0 = MSB = register)

__device__ __forceinline__ void ry_gate(float& a0, float& a1, int w, int lane,
                                        float c, float s) {
  if (w == 0) {
    float n0 = c * a0 - s * a1;
    float n1 = s * a0 + c * a1;
    a0 = n0; a1 = n1;
  } else {
    int m = 1 << (6 - w);
    float p0 = __shfl_xor(a0, m);
    float p1 = __shfl_xor(a1, m);
    if (lane & m) {
      a0 = s * p0 + c * a0;
      a1 = s * p1 + c * a1;
    } else {
      a0 = c * a0 - s * p0;
      a1 = c * a1 - s * p1;
    }
  }
}

// merged {RY(th1,t); CNOT(cw,t); RY(th2,t)}: one shfl pair instead of three
// chain steps. c-bit=0: RY(th1+th2); c-bit=1: (x,y)->(-sm*x+cm*y, cm*x+sm*y),
// cp=cos(h1+h2), sp=sin(h1+h2), cm=cos(h2-h1), sm=sin(h2-h1) (h=theta/2).
__device__ __forceinline__ void pair_op(float& a0, float& a1, int cw, int tw,
                                        int lane, float c1, float s1,
                                        float c2, float s2) {
  float cp = c1 * c2 - s1 * s2;
  float sp = s1 * c2 + c1 * s2;
  float cm = c1 * c2 + s1 * s2;
  float sm = s2 * c1 - c2 * s1;
  if (tw == 0) {            // target wire 0: register-local pair, no shfl
    int mc = 1 << (6 - cw);
    bool cb = (lane & mc) != 0;
    float n0 = cb ? (cm * a1 - sm * a0) : (cp * a0 - sp * a1);
    float n1 = cb ? (cm * a0 + sm * a1) : (sp * a0 + cp * a1);
    a0 = n0; a1 = n1;
  } else if (cw == 0) {     // control wire 0: c-bit IS the register index
    int mt = 1 << (6 - tw);
    float p0 = __shfl_xor(a0, mt);
    float p1 = __shfl_xor(a1, mt);
    bool tb = (lane & mt) != 0;
    a0 = tb ? (sp * p0 + cp * a0) : (cp * a0 - sp * p0);
    a1 = tb ? (sm * a1 + cm * p1) : (cm * p1 - sm * a1);
  } else {                  // both lane bits
    int mt = 1 << (6 - tw), mc = 1 << (6 - cw);
    float p0 = __shfl_xor(a0, mt);
    float p1 = __shfl_xor(a1, mt);
    bool tb = (lane & mt) != 0, cb = (lane & mc) != 0;
    float own = cb ? (tb ? sm : -sm) : cp;
    float par = cb ? cm : (tb ? sp : -sp);
    a0 = own * a0 + par * p0;
    a1 = own * a1 + par * p1;
  }
}

// ------- kernel 1: build U, store in MFMA B-FRAGMENT order (f16) -----------
// cs-table layout per layer j (qc region at qb, 6*sq entries):
//   sweep1: qb+i (wire i) | ring: qb+sq+2i,+1 | sweep2: qb+3sq+w (wire w) |
//   skip: qb+4sq+2i,+1 ; then qp region pb: 2(sq-1) entries.
// OPT: sweep2 RYs for wires w>=1 are folded into the skip PAIR whose target
// is w (targets distinct; wire becomes control only AFTER being target).
// Wire 0's sweep2 RY can't cross skip-PAIR 0 (control = wire 0) — emitted
// standalone (register-local, free). Saves 21 shfl steps.
__global__ __launch_bounds__(64) void basis_kernel(
    const float* __restrict__ qc1, const float* __restrict__ qc2,
    const float* __restrict__ qc3, const float* __restrict__ qc4,
    const float* __restrict__ qc5, const float* __restrict__ qc6,
    const float* __restrict__ qp1, const float* __restrict__ qp2,
    const float* __restrict__ qp3, const float* __restrict__ qp4,
    const float* __restrict__ qp5, const float* __restrict__ qp6,
    const float* __restrict__ qf, _Float16* __restrict__ wt) {
  __shared__ float2 cs[208];
  int lane = threadIdx.x;

  // angles laid out flat: [QC1,QP1,QC2,QP2,...,QC6,QP6,QF] -> (cos,sin)(a/2)
  {
    const float* arrs[13] = {qc1, qp1, qc2, qp2, qc3, qp3, qc4,
                             qp4, qc5, qp5, qc6, qp6, qf};
    const int sizes[13] = {42, 12, 36, 10, 30, 8, 24, 6, 18, 4, 12, 2, 1};
    for (int t = lane; t < 205; t += 64) {
      int base = 0; float ang = 0.f;
#pragma unroll
      for (int s2 = 0; s2 < 13; ++s2) {
        if (t >= base && t < base + sizes[s2]) ang = arrs[s2][t - base];
        base += sizes[s2];
      }
      float h = 0.5f * ang;
      cs[t] = make_float2(cosf(h), sinf(h));
    }
  }
  __syncthreads();

  int k = blockIdx.x;  // basis column
  float a0 = ((k >> 6) == 0 && (k & 63) == lane) ? 1.0f : 0.0f;
  float a1 = ((k >> 6) == 1 && (k & 63) == lane) ? 1.0f : 0.0f;

  const int qcstep[6] = {4, 1, 2, 1, 1, 1};
  int idx = 0;
#pragma unroll
  for (int j = 0; j < 6; ++j) {
    int sq = 7 - j;
    int step = qcstep[j];
    int qb = idx;
    // sweep 1
    for (int i = 0; i < sq; ++i) {
      float2 v = cs[qb + i];
      ry_gate(a0, a1, i, lane, v.x, v.y);
    }
    // ring entangle (merged PAIRs)
    for (int i = 0; i < sq; ++i) {
      float2 v1 = cs[qb + sq + 2 * i], v2 = cs[qb + sq + 2 * i + 1];
      if (i == 0) pair_op(a0, a1, sq - 1, 0, lane, v1.x, v1.y, v2.x, v2.y);
      else { int w = sq - i; pair_op(a0, a1, w - 1, w, lane, v1.x, v1.y, v2.x, v2.y); }
    }
    // sweep 2: only wire 0 standalone; w>=1 folded into skip PAIRs below
    {
      float2 v = cs[qb + 3 * sq];
      ry_gate(a0, a1, 0, lane, v.x, v.y);
    }
    // skip entangle with sweep2(w>=1) folded into th1 (exact angle-sum)
    {
      int control = 0, controled = step;
      for (int i = 0; i < sq; ++i) {
        float2 v1 = cs[qb + 4 * sq + 2 * i], v2 = cs[qb + 4 * sq + 2 * i + 1];
        float ca = v1.x, sa = v1.y;
        if (controled != 0) {
          float2 vs = cs[qb + 3 * sq + controled];
          ca = vs.x * v1.x - vs.y * v1.y;
          sa = vs.y * v1.x + vs.x * v1.y;
        }
        pair_op(a0, a1, control, controled, lane, ca, sa, v2.x, v2.y);
        control = controled; controled = (controled + step) % sq;
      }
    }
    idx += 6 * sq;
    int pb = idx;
    // qp chain (merged PAIRs)
    for (int i = 0; i < sq - 1; ++i) {
      float2 v1 = cs[pb + 2 * i], v2 = cs[pb + 2 * i + 1];
      pair_op(a0, a1, i, i + 1, lane, v1.x, v1.y, v2.x, v2.y);
    }
    idx += 2 * (sq - 1);
  }
  {  // final QF rotation (idx == 204)
    float2 v = cs[idx];
    ry_gate(a0, a1, 0, lane, v.x, v.y);
  }

  // scatter to fragment order:
  //   element (n,k): f16 idx = ((k>>5)*8+(n>>4))*512 + ((k>>3)&3)*128 + (n&15)*8 + (k&7)
  {
    int ks = k >> 5, khi = (k >> 3) & 3, j = k & 7;
    int nf0 = lane >> 4, lr0 = lane & 15;
    wt[(ks * 8 + nf0) * 512 + khi * 128 + lr0 * 8 + j] = (_Float16)a0;
    wt[(ks * 8 + nf0 + 4) * 512 + khi * 128 + lr0 * 8 + j] = (_Float16)a1;
  }
}

// ---------------- kernel 2: Z = X * U^T, out = row-half prob ----------------
// Round-6 structure (best measured). X loads NON-TEMPORAL (evict-first): X
// streams 134 MB once/pass through each XCD's 4 MB L2; avoid thrash. W stays
// normal (reused). nt-load needs clang-native vector type, not HIP float4.
__device__ __forceinline__ fvec4 ntload(const float* p) {
  return __builtin_nontemporal_load((const fvec4*)p);
}

__global__ __launch_bounds__(256, 4) void qcnn_gemm(
    const float* __restrict__ X, const _Float16* __restrict__ wt,
    float* __restrict__ out, int M) {
  __shared__ uint4 ldsbuf[2048];  // 32 KB: W in fragment order
  int tid = threadIdx.x;
  int wave = tid >> 6, lane = tid & 63;
  int lr = lane & 15;
  int g = lane >> 4;
  int lk = g * 8;

  size_t base0 = (size_t)blockIdx.x * 256 + wave * 16;  // this wave's row base

  // prefetch iter-0 X loads (in flight during LDS staging + barrier)
  fvec4 v0[4], v1[4];
  if (base0 < (size_t)M) {
    const float* xp = X + (base0 + lr) * 128 + lk;
#pragma unroll
    for (int ks = 0; ks < 4; ++ks) {
      v0[ks] = ntload(xp + ks * 32);
      v1[ks] = ntload(xp + ks * 32 + 4);
    }
  }

  // stage W -> LDS: straight linear copy, fully coalesced
  {
    const uint4* wv = (const uint4*)wt;
#pragma unroll
    for (int c = 0; c < 8; ++c) ldsbuf[c * 256 + tid] = wv[c * 256 + tid];
  }
  __syncthreads();

  const char* bbase = (const char*)ldsbuf + lane * 16;

#pragma unroll
  for (int t = 0; t < 4; ++t) {
    size_t rb = base0 + (size_t)t * 64;
    if (rb < (size_t)M) {
      // convert current tile to f16 A-fragments (frees v0/v1)
      f16x8 a[4];
#pragma unroll
      for (int ks = 0; ks < 4; ++ks) {
        auto p0 = __builtin_amdgcn_cvt_pkrtz(v0[ks][0], v0[ks][1]);
        auto p1 = __builtin_amdgcn_cvt_pkrtz(v0[ks][2], v0[ks][3]);
        auto p2 = __builtin_amdgcn_cvt_pkrtz(v1[ks][0], v1[ks][1]);
        auto p3 = __builtin_amdgcn_cvt_pkrtz(v1[ks][2], v1[ks][3]);
        f16x8 f;
        f[0] = (_Float16)p0[0]; f[1] = (_Float16)p0[1];
        f[2] = (_Float16)p1[0]; f[3] = (_Float16)p1[1];
        f[4] = (_Float16)p2[0]; f[5] = (_Float16)p2[1];
        f[6] = (_Float16)p3[0]; f[7] = (_Float16)p3[1];
        a[ks] = f;
      }

      // issue next tile's loads early — in flight during MFMA + epilogue
      if (t < 3) {
        size_t rn = base0 + (size_t)(t + 1) * 64;
        if (rn < (size_t)M) {
          const float* xp = X + (rn + lr) * 128 + lk;
#pragma unroll
          for (int ks = 0; ks < 4; ++ks) {
            v0[ks] = ntload(xp + ks * 32);
            v1[ks] = ntload(xp + ks * 32 + 4);
          }
        }
      }

      f32x4 acc[8];
#pragma unroll
      for (int nf = 0; nf < 8; ++nf) acc[nf] = (f32x4){0.f, 0.f, 0.f, 0.f};

#pragma unroll
      for (int ks = 0; ks < 4; ++ks) {
#pragma unroll
        for (int nf = 0; nf < 8; ++nf) {
          f16x8 b = *(const f16x8*)(bbase + (ks * 8 + nf) * 1024);
          acc[nf] = __builtin_amdgcn_mfma_f32_16x16x32_f16(a[ks], b, acc[nf], 0, 0, 0);
        }
      }

      // epilogue: s0 = sum_{n<64} z^2, s1 = sum_{n>=64} z^2 per row
      float s0[4], s1[4];
#pragma unroll
      for (int r = 0; r < 4; ++r) {
        float t0 = 0.f, t1 = 0.f;
#pragma unroll
        for (int nf = 0; nf < 4; ++nf) t0 += acc[nf][r] * acc[nf][r];
#pragma unroll
        for (int nf = 4; nf < 8; ++nf) t1 += acc[nf][r] * acc[nf][r];
        s0[r] = t0; s1[r] = t1;
      }
#pragma unroll
      for (int d = 1; d < 16; d <<= 1) {  // reduce across the 16-lane group
#pragma unroll
        for (int r = 0; r < 4; ++r) {
          s0[r] += __shfl_xor(s0[r], d);
          s1[r] += __shfl_xor(s1[r], d);
        }
      }
      size_t row = rb + g * 4;
#pragma unroll
      for (int r = 0; r < 4; ++r) {
        if ((lane & 15) == r) {
          float inv = 1.0f / (s0[r] + s1[r]);
          *(float2*)(out + (row + r) * 2) =
              make_float2(s0[r] * inv, s1[r] * inv);
        }
      }
    }
  }
}

// ---------------------------------------------------------------------------
extern "C" void kernel_launch(void* const* d_in, const int* in_sizes, int n_in,
                              void* d_out, int out_size, void* d_ws,
                              size_t ws_size, hipStream_t stream) {
  const float* X = (const float*)d_in[0];
  _Float16* wt = (_Float16*)d_ws;  // 128*128 f16 = 32 KB, fragment order

  // setup_inputs() dict order is INTERLEAVED: x, QC1, QP1, QC2, QP2, ...,
  // QC6, QP6, QF.
  basis_kernel<<<128, 64, 0, stream>>>(
      /*qc1*/ (const float*)d_in[1], /*qc2*/ (const float*)d_in[3],
      /*qc3*/ (const float*)d_in[5], /*qc4*/ (const float*)d_in[7],
      /*qc5*/ (const float*)d_in[9], /*qc6*/ (const float*)d_in[11],
      /*qp1*/ (const float*)d_in[2], /*qp2*/ (const float*)d_in[4],
      /*qp3*/ (const float*)d_in[6], /*qp4*/ (const float*)d_in[8],
      /*qp5*/ (const float*)d_in[10], /*qp6*/ (const float*)d_in[12],
      /*qf*/ (const float*)d_in[13], wt);

  int M = in_sizes[0] / 128;   // 262144
  int nblk = (M + 255) / 256;  // 1024 blocks of 256 rows
  qcnn_gemm<<<nblk, 256, 0, stream>>>(X, wt, (float*)d_out, M);
}

// Round 17
// 38.628 us; speedup vs baseline: 1.0669x; 1.0669x over previous
//
#include <hip/hip_runtime.h>

typedef _Float16 f16x8 __attribute__((ext_vector_type(8)));
typedef float f32x4 __attribute__((ext_vector_type(4)));

// ---------------- gate primitives (state: 128 amps, 2 per lane) -------------
// amp index i = (r<<6) | lane, wire w <-> bit (6-w) (wire 0 = MSB = register)

__device__ __forceinline__ void ry_gate(float& a0, float& a1, int w, int lane,
                                        float c, float s) {
  if (w == 0) {
    float n0 = c * a0 - s * a1;
    float n1 = s * a0 + c * a1;
    a0 = n0; a1 = n1;
  } else {
    int m = 1 << (6 - w);
    float p0 = __shfl_xor(a0, m);
    float p1 = __shfl_xor(a1, m);
    if (lane & m) {
      a0 = s * p0 + c * a0;
      a1 = s * p1 + c * a1;
    } else {
      a0 = c * a0 - s * p0;
      a1 = c * a1 - s * p1;
    }
  }
}

// merged {RY(th1,t); CNOT(cw,t); RY(th2,t)}: one shfl pair instead of three
// chain steps. c-bit=0: RY(th1+th2); c-bit=1: (x,y)->(-sm*x+cm*y, cm*x+sm*y),
// cp=cos(h1+h2), sp=sin(h1+h2), cm=cos(h2-h1), sm=sin(h2-h1) (h=theta/2).
__device__ __forceinline__ void pair_op(float& a0, float& a1, int cw, int tw,
                                        int lane, float c1, float s1,
                                        float c2, float s2) {
  float cp = c1 * c2 - s1 * s2;
  float sp = s1 * c2 + c1 * s2;
  float cm = c1 * c2 + s1 * s2;
  float sm = s2 * c1 - c2 * s1;
  if (tw == 0) {            // target wire 0: register-local pair, no shfl
    int mc = 1 << (6 - cw);
    bool cb = (lane & mc) != 0;
    float n0 = cb ? (cm * a1 - sm * a0) : (cp * a0 - sp * a1);
    float n1 = cb ? (cm * a0 + sm * a1) : (sp * a0 + cp * a1);
    a0 = n0; a1 = n1;
  } else if (cw == 0) {     // control wire 0: c-bit IS the register index
    int mt = 1 << (6 - tw);
    float p0 = __shfl_xor(a0, mt);
    float p1 = __shfl_xor(a1, mt);
    bool tb = (lane & mt) != 0;
    a0 = tb ? (sp * p0 + cp * a0) : (cp * a0 - sp * p0);
    a1 = tb ? (sm * a1 + cm * p1) : (cm * p1 - sm * a1);
  } else {                  // both lane bits
    int mt = 1 << (6 - tw), mc = 1 << (6 - cw);
    float p0 = __shfl_xor(a0, mt);
    float p1 = __shfl_xor(a1, mt);
    bool tb = (lane & mt) != 0, cb = (lane & mc) != 0;
    float own = cb ? (tb ? sm : -sm) : cp;
    float par = cb ? cm : (tb ? sp : -sp);
    a0 = own * a0 + par * p0;
    a1 = own * a1 + par * p1;
  }
}

// ------- kernel 1: build U, store in MFMA B-FRAGMENT order (f16) -----------
// cs-table layout per layer j (qc region at qb, 6*sq entries):
//   sweep1: qb+i (wire i) | ring: qb+sq+2i,+1 | sweep2: qb+3sq+w (wire w) |
//   skip: qb+4sq+2i,+1 ; then qp region pb: 2(sq-1) entries.
// sweep2 RYs for wires w>=1 folded into the skip PAIR targeting w (exact
// angle-sum; targets distinct, wire becomes control only AFTER being target).
// Wire 0's sweep2 RY stays standalone (register-local, free).
__global__ __launch_bounds__(64) void basis_kernel(
    const float* __restrict__ qc1, const float* __restrict__ qc2,
    const float* __restrict__ qc3, const float* __restrict__ qc4,
    const float* __restrict__ qc5, const float* __restrict__ qc6,
    const float* __restrict__ qp1, const float* __restrict__ qp2,
    const float* __restrict__ qp3, const float* __restrict__ qp4,
    const float* __restrict__ qp5, const float* __restrict__ qp6,
    const float* __restrict__ qf, _Float16* __restrict__ wt) {
  __shared__ float2 cs[208];
  int lane = threadIdx.x;

  // angles laid out flat: [QC1,QP1,QC2,QP2,...,QC6,QP6,QF] -> (cos,sin)(a/2)
  {
    const float* arrs[13] = {qc1, qp1, qc2, qp2, qc3, qp3, qc4,
                             qp4, qc5, qp5, qc6, qp6, qf};
    const int sizes[13] = {42, 12, 36, 10, 30, 8, 24, 6, 18, 4, 12, 2, 1};
    for (int t = lane; t < 205; t += 64) {
      int base = 0; float ang = 0.f;
#pragma unroll
      for (int s2 = 0; s2 < 13; ++s2) {
        if (t >= base && t < base + sizes[s2]) ang = arrs[s2][t - base];
        base += sizes[s2];
      }
      float h = 0.5f * ang;
      cs[t] = make_float2(cosf(h), sinf(h));
    }
  }
  __syncthreads();

  int k = blockIdx.x;  // basis column
  float a0 = ((k >> 6) == 0 && (k & 63) == lane) ? 1.0f : 0.0f;
  float a1 = ((k >> 6) == 1 && (k & 63) == lane) ? 1.0f : 0.0f;

  const int qcstep[6] = {4, 1, 2, 1, 1, 1};
  int idx = 0;
#pragma unroll
  for (int j = 0; j < 6; ++j) {
    int sq = 7 - j;
    int step = qcstep[j];
    int qb = idx;
    // sweep 1
    for (int i = 0; i < sq; ++i) {
      float2 v = cs[qb + i];
      ry_gate(a0, a1, i, lane, v.x, v.y);
    }
    // ring entangle (merged PAIRs)
    for (int i = 0; i < sq; ++i) {
      float2 v1 = cs[qb + sq + 2 * i], v2 = cs[qb + sq + 2 * i + 1];
      if (i == 0) pair_op(a0, a1, sq - 1, 0, lane, v1.x, v1.y, v2.x, v2.y);
      else { int w = sq - i; pair_op(a0, a1, w - 1, w, lane, v1.x, v1.y, v2.x, v2.y); }
    }
    // sweep 2: only wire 0 standalone; w>=1 folded into skip PAIRs below
    {
      float2 v = cs[qb + 3 * sq];
      ry_gate(a0, a1, 0, lane, v.x, v.y);
    }
    // skip entangle with sweep2(w>=1) folded into th1 (exact angle-sum)
    {
      int control = 0, controled = step;
      for (int i = 0; i < sq; ++i) {
        float2 v1 = cs[qb + 4 * sq + 2 * i], v2 = cs[qb + 4 * sq + 2 * i + 1];
        float ca = v1.x, sa = v1.y;
        if (controled != 0) {
          float2 vs = cs[qb + 3 * sq + controled];
          ca = vs.x * v1.x - vs.y * v1.y;
          sa = vs.y * v1.x + vs.x * v1.y;
        }
        pair_op(a0, a1, control, controled, lane, ca, sa, v2.x, v2.y);
        control = controled; controled = (controled + step) % sq;
      }
    }
    idx += 6 * sq;
    int pb = idx;
    // qp chain (merged PAIRs)
    for (int i = 0; i < sq - 1; ++i) {
      float2 v1 = cs[pb + 2 * i], v2 = cs[pb + 2 * i + 1];
      pair_op(a0, a1, i, i + 1, lane, v1.x, v1.y, v2.x, v2.y);
    }
    idx += 2 * (sq - 1);
  }
  {  // final QF rotation (idx == 204)
    float2 v = cs[idx];
    ry_gate(a0, a1, 0, lane, v.x, v.y);
  }

  // scatter to fragment order:
  //   element (n,k): f16 idx = ((k>>5)*8+(n>>4))*512 + ((k>>3)&3)*128 + (n&15)*8 + (k&7)
  {
    int ks = k >> 5, khi = (k >> 3) & 3, j = k & 7;
    int nf0 = lane >> 4, lr0 = lane & 15;
    wt[(ks * 8 + nf0) * 512 + khi * 128 + lr0 * 8 + j] = (_Float16)a0;
    wt[(ks * 8 + nf0 + 4) * 512 + khi * 128 + lr0 * 8 + j] = (_Float16)a1;
  }
}

// ---------------- kernel 2: Z = X * U^T, out = row-half prob ----------------
// Round-6/14 structure (best measured: warm ~21 us = L3-fabric stream
// ceiling). NORMAL X loads — round-16 A/B showed non-temporal loads cost
// ~2 us (stream is fabric-bound, not L2-thrash-bound).
__global__ __launch_bounds__(256, 4) void qcnn_gemm(
    const float* __restrict__ X, const _Float16* __restrict__ wt,
    float* __restrict__ out, int M) {
  __shared__ uint4 ldsbuf[2048];  // 32 KB: W in fragment order
  int tid = threadIdx.x;
  int wave = tid >> 6, lane = tid & 63;
  int lr = lane & 15;
  int g = lane >> 4;
  int lk = g * 8;

  size_t base0 = (size_t)blockIdx.x * 256 + wave * 16;  // this wave's row base

  // prefetch iter-0 X loads (in flight during LDS staging + barrier)
  float4 v0[4], v1[4];
  if (base0 < (size_t)M) {
    const float* xp = X + (base0 + lr) * 128 + lk;
#pragma unroll
    for (int ks = 0; ks < 4; ++ks) {
      v0[ks] = *(const float4*)(xp + ks * 32);
      v1[ks] = *(const float4*)(xp + ks * 32 + 4);
    }
  }

  // stage W -> LDS: straight linear copy, fully coalesced
  {
    const uint4* wv = (const uint4*)wt;
#pragma unroll
    for (int c = 0; c < 8; ++c) ldsbuf[c * 256 + tid] = wv[c * 256 + tid];
  }
  __syncthreads();

  const char* bbase = (const char*)ldsbuf + lane * 16;

#pragma unroll
  for (int t = 0; t < 4; ++t) {
    size_t rb = base0 + (size_t)t * 64;
    if (rb < (size_t)M) {
      // convert current tile to f16 A-fragments (frees v0/v1)
      f16x8 a[4];
#pragma unroll
      for (int ks = 0; ks < 4; ++ks) {
        auto p0 = __builtin_amdgcn_cvt_pkrtz(v0[ks].x, v0[ks].y);
        auto p1 = __builtin_amdgcn_cvt_pkrtz(v0[ks].z, v0[ks].w);
        auto p2 = __builtin_amdgcn_cvt_pkrtz(v1[ks].x, v1[ks].y);
        auto p3 = __builtin_amdgcn_cvt_pkrtz(v1[ks].z, v1[ks].w);
        f16x8 f;
        f[0] = (_Float16)p0[0]; f[1] = (_Float16)p0[1];
        f[2] = (_Float16)p1[0]; f[3] = (_Float16)p1[1];
        f[4] = (_Float16)p2[0]; f[5] = (_Float16)p2[1];
        f[6] = (_Float16)p3[0]; f[7] = (_Float16)p3[1];
        a[ks] = f;
      }

      // issue next tile's loads early — in flight during MFMA + epilogue
      if (t < 3) {
        size_t rn = base0 + (size_t)(t + 1) * 64;
        if (rn < (size_t)M) {
          const float* xp = X + (rn + lr) * 128 + lk;
#pragma unroll
          for (int ks = 0; ks < 4; ++ks) {
            v0[ks] = *(const float4*)(xp + ks * 32);
            v1[ks] = *(const float4*)(xp + ks * 32 + 4);
          }
        }
      }

      f32x4 acc[8];
#pragma unroll
      for (int nf = 0; nf < 8; ++nf) acc[nf] = (f32x4){0.f, 0.f, 0.f, 0.f};

#pragma unroll
      for (int ks = 0; ks < 4; ++ks) {
#pragma unroll
        for (int nf = 0; nf < 8; ++nf) {
          f16x8 b = *(const f16x8*)(bbase + (ks * 8 + nf) * 1024);
          acc[nf] = __builtin_amdgcn_mfma_f32_16x16x32_f16(a[ks], b, acc[nf], 0, 0, 0);
        }
      }

      // epilogue: s0 = sum_{n<64} z^2, s1 = sum_{n>=64} z^2 per row
      float s0[4], s1[4];
#pragma unroll
      for (int r = 0; r < 4; ++r) {
        float t0 = 0.f, t1 = 0.f;
#pragma unroll
        for (int nf = 0; nf < 4; ++nf) t0 += acc[nf][r] * acc[nf][r];
#pragma unroll
        for (int nf = 4; nf < 8; ++nf) t1 += acc[nf][r] * acc[nf][r];
        s0[r] = t0; s1[r] = t1;
      }
#pragma unroll
      for (int d = 1; d < 16; d <<= 1) {  // reduce across the 16-lane group
#pragma unroll
        for (int r = 0; r < 4; ++r) {
          s0[r] += __shfl_xor(s0[r], d);
          s1[r] += __shfl_xor(s1[r], d);
        }
      }
      size_t row = rb + g * 4;
#pragma unroll
      for (int r = 0; r < 4; ++r) {
        if ((lane & 15) == r) {
          float inv = 1.0f / (s0[r] + s1[r]);
          *(float2*)(out + (row + r) * 2) =
              make_float2(s0[r] * inv, s1[r] * inv);
        }
      }
    }
  }
}

// ---------------------------------------------------------------------------
extern "C" void kernel_launch(void* const* d_in, const int* in_sizes, int n_in,
                              void* d_out, int out_size, void* d_ws,
                              size_t ws_size, hipStream_t stream) {
  const float* X = (const float*)d_in[0];
  _Float16* wt = (_Float16*)d_ws;  // 128*128 f16 = 32 KB, fragment order

  // setup_inputs() dict order is INTERLEAVED: x, QC1, QP1, QC2, QP2, ...,
  // QC6, QP6, QF.
  basis_kernel<<<128, 64, 0, stream>>>(
      /*qc1*/ (const float*)d_in[1], /*qc2*/ (const float*)d_in[3],
      /*qc3*/ (const float*)d_in[5], /*qc4*/ (const float*)d_in[7],
      /*qc5*/ (const float*)d_in[9], /*qc6*/ (const float*)d_in[11],
      /*qp1*/ (const float*)d_in[2], /*qp2*/ (const float*)d_in[4],
      /*qp3*/ (const float*)d_in[6], /*qp4*/ (const float*)d_in[8],
      /*qp5*/ (const float*)d_in[10], /*qp6*/ (const float*)d_in[12],
      /*qf*/ (const float*)d_in[13], wt);

  int M = in_sizes[0] / 128;   // 262144
  int nblk = (M + 255) / 256;  // 1024 blocks of 256 rows
  qcnn_gemm<<<nblk, 256, 0, stream>>>(X, wt, (float*)d_out, M);
}